// Round 2
// baseline (949.230 us; speedup 1.0000x reference)
//
#include <hip/hip_runtime.h>
#include <hip/hip_bf16.h>

#define N_    32
#define T_    1600
#define C_    1024
#define S_    200
#define L_    401       // 2*S+1
#define LP_   512       // padded
#define BLANK_ 4
#define LN2_  0.69314718055994531f
#define L2E_  1.44269504088896341f
#define DEPTH 16        // LDS ring rows (power of 2)
#define PD    14        // prefetch distance in rows (<= DEPTH-2: slot-reuse safety)

#if __has_builtin(__builtin_amdgcn_exp2f)
#define EXP2(x) __builtin_amdgcn_exp2f(x)
#else
#define EXP2(x) exp2f(x)
#endif
#if __has_builtin(__builtin_amdgcn_rcpf)
#define RCP(x) __builtin_amdgcn_rcpf(x)
#else
#define RCP(x) (1.0f / (x))
#endif

// async global->LDS, 16B per lane, dest = wave-uniform base + lane*16
__device__ __forceinline__ void gload_lds16(const float* gsrc, float* ldst) {
  __builtin_amdgcn_global_load_lds(
      (const __attribute__((address_space(1))) unsigned int*)gsrc,
      (__attribute__((address_space(3))) unsigned int*)ldst, 16, 0, 0);
}

// Kernel 1: one wave per (n,t) row. Wave-shuffle softmax, row staged in LDS,
// gather ext-label classes, write LINEAR probabilities P[n][t][l].
// Junk positions (l > 2*tgt_len[n], never read) are zeroed so their alphas
// stay exactly 0 and never pollute the renorm max in k_ctc.
__global__ __launch_bounds__(256)
void k_softmax_gather(const float* __restrict__ logits,
                      const int* __restrict__ targets,
                      const int* __restrict__ tgt_len,
                      float* __restrict__ P) {
  const int row  = blockIdx.x * 4 + (threadIdx.x >> 6);  // n*T_ + t
  const int lane = threadIdx.x & 63;
  const int wv   = threadIdx.x >> 6;
  const int n    = row / T_;
  const float* x = logits + (size_t)row * C_;
  __shared__ float sh[4][C_];

  float4 v[4];
#pragma unroll
  for (int i = 0; i < 4; ++i)
    v[i] = reinterpret_cast<const float4*>(x)[i * 64 + lane];

  float mx = v[0].x;
#pragma unroll
  for (int i = 0; i < 4; ++i)
    mx = fmaxf(mx, fmaxf(fmaxf(v[i].x, v[i].y), fmaxf(v[i].z, v[i].w)));
#pragma unroll
  for (int i = 1; i < 64; i <<= 1) mx = fmaxf(mx, __shfl_xor(mx, i));

  float s = 0.0f;
#pragma unroll
  for (int i = 0; i < 4; ++i) {
    s += EXP2((v[i].x - mx) * L2E_) + EXP2((v[i].y - mx) * L2E_)
       + EXP2((v[i].z - mx) * L2E_) + EXP2((v[i].w - mx) * L2E_);
  }
#pragma unroll
  for (int i = 1; i < 64; i <<= 1) s += __shfl_xor(s, i);
  float rz = RCP(s);

#pragma unroll
  for (int i = 0; i < 4; ++i)
    reinterpret_cast<float4*>(sh[wv])[i * 64 + lane] = v[i];
  __syncthreads();

  const int* tg = targets + n * S_;
  const int lmax = 2 * tgt_len[n];   // live region: l in [0, 2*tl]
  float* out = P + (size_t)row * LP_;
#pragma unroll
  for (int i = 0; i < 8; ++i) {
    int l = lane + i * 64;
    float p = 0.0f;
    if (l <= lmax) {
      int c = (l & 1) ? tg[(l - 1) >> 1] : BLANK_;
      p = EXP2((sh[wv][c] - mx) * L2E_) * rz;
    }
    out[l] = p;
  }
}

// Kernel 2: f64 linear-space CTC forward, ONE wave per sequence. Lane owns 8
// contiguous positions. Only ONE cross-lane value per step (alpha[l-1] for
// j=0), shuffled one step AHEAD so bpermute latency hides under the f64 issue
// stream.
//
// THIS ROUND: R1's VGPR ping-pong was defeated by the register-pressure
// heuristic (VGPR_Count=84 -- the 128-VGPR double buffer never materialized;
// ~80 cyc/step of load-latency stall remained). Fix: prefetch through an LDS
// ring via global_load_lds (no dest VGPR => compiler CANNOT sink the loads).
// Depth-16 ring, prefetch distance 14 rows (~1600 cyc issue-to-use), manual
// counted s_waitcnt vmcnt(26) per step (28 outstanding, drain only the oldest
// row -- never 0), ds_read_b128 one row ahead into statically-named ping-pong
// regs (2x unrolled loop). Slot reuse safe: stage at step t overwrites the
// slot of row t-2, fully consumed at step t-2. Math / renorm cadence /
// epilogue unchanged.
__global__ __launch_bounds__(64, 1)
void k_ctc(const float* __restrict__ P,
           const int* __restrict__ targets,
           const int* __restrict__ in_len,
           const int* __restrict__ tgt_len,
           float* __restrict__ nll_out) {
  const int n = blockIdx.x;
  const int lane = threadIdx.x;
  const int Tn = in_len[n];
  const float* g = P + (size_t)n * T_ * LP_;
  const int* tg = targets + n * S_;

  __shared__ __align__(16) float ring[DEPTH][LP_];  // 16 x 2KB = 32 KB
  __shared__ double sa[LP_];

  // skip multipliers for odd positions j=1,3,5,7 -> label index m0+0..3
  const int m0 = lane * 4;
  auto skv = [&](int m) -> double {
    int mi = (m >= 1 && m < S_) ? m : 1;     // clamp: no OOB read
    return (m >= 1 && m < S_ && tg[mi] != tg[mi - 1]) ? 1.0 : 0.0;
  };
  const double sk1 = skv(m0), sk3 = skv(m0 + 1);
  const double sk5 = skv(m0 + 2), sk7 = skv(m0 + 3);

  double a0 = 0.0, a1 = 0.0, a2 = 0.0, a3 = 0.0;
  double a4 = 0.0, a5 = 0.0, a6 = 0.0, a7 = 0.0;
  double up = 0.0;   // alpha(t-1, lane*8 - 1): shuffled during previous step
  if (lane == 0) { a0 = (double)g[0]; a1 = (double)g[1]; }
  int Etot = 0;      // true alpha = a * 2^Etot (wave-uniform)

  const int src = (lane + 63) & 63;

  auto step = [&](const float4& A, const float4& B) {
    // a7n/a6n first: lane-local only -> shuffle for NEXT step issues early
    double a7n = (a7 + a6 + sk7 * a5) * (double)B.w;
    double a6n = (a6 + a5) * (double)B.z;
    double upn = __shfl(a7n, src);           // consumed next step
    double a5n = (a5 + a4 + sk5 * a3) * (double)B.y;
    double a4n = (a4 + a3) * (double)B.x;
    double a3n = (a3 + a2 + sk3 * a1) * (double)A.w;
    double a2n = (a2 + a1) * (double)A.z;
    double a1n = (a1 + a0 + sk1 * up) * (double)A.y;  // up: already in regs
    double a0n = (a0 + up) * (double)A.x;             // even: no skip ever
    if (lane == 0) upn = 0.0;                // no predecessor
    a0 = a0n; a1 = a1n; a2 = a2n; a3 = a3n;
    a4 = a4n; a5 = a5n; a6 = a6n; a7 = a7n;
    up = upn;
  };

  auto renorm = [&]() {
    int h = max(max(max(__double2hiint(a0), __double2hiint(a1)),
                    max(__double2hiint(a2), __double2hiint(a3))),
                max(max(__double2hiint(a4), __double2hiint(a5)),
                    max(__double2hiint(a6), __double2hiint(a7))));
#pragma unroll
    for (int i = 1; i < 64; i <<= 1) h = max(h, __shfl_xor(h, i));
    int R = 1021 - (h >> 20);   // scale wave max into [2^-2, 2^-1)
    a0 = ldexp(a0, R); a1 = ldexp(a1, R); a2 = ldexp(a2, R); a3 = ldexp(a3, R);
    a4 = ldexp(a4, R); a5 = ldexp(a5, R); a6 = ldexp(a6, R); a7 = ldexp(a7, R);
    up = ldexp(up, R);          // pipelined boundary value rides along
    Etot -= R;
  };

  // stage row tt into its ring slot via LDS-DMA (slot from UNclamped index so
  // rotation stays consistent; clamped rows are prefetch garbage, never
  // consumed by an executed step)
  auto stage = [&](int tt) {
    int slot = tt & (DEPTH - 1);
    if (tt > T_ - 1) tt = T_ - 1;
    const float* s0 = g + (size_t)tt * LP_ + (lane << 3);
    gload_lds16(s0,     &ring[slot][0]);    // lane's first 16B -> base + lane*16
    gload_lds16(s0 + 4, &ring[slot][256]);  // lane's next  16B -> base+1KB + lane*16
  };

  auto dsread = [&](int tt, float4& A, float4& B) {
    const float* b = &ring[tt & (DEPTH - 1)][lane << 2];
    A = *reinterpret_cast<const float4*>(b);
    B = *reinterpret_cast<const float4*>(b + 256);
  };

  // prologue: stage rows 1..PD (28 loads in flight), land row 1, read it
#pragma unroll
  for (int r = 1; r <= PD; ++r) stage(r);
  asm volatile("s_waitcnt vmcnt(26)" ::: "memory");
  float4 A0, B0, A1, B1;
  dsread(1, A0, B0);

  const int nsteps = Tn - 1;   // steps t = 1 .. Tn-1
  int t = 1;
  while (t + 1 <= nsteps) {
    // step t: regs (A0,B0) hold row t
    stage(t + PD);
    asm volatile("s_waitcnt vmcnt(26)" ::: "memory");  // row t+1 landed
    dsread(t + 1, A1, B1);
    step(A0, B0);
    if ((t & 31) == 0) renorm();   // every 32 steps; tail gap <= 31
    ++t;
    // step t: regs (A1,B1) hold row t
    stage(t + PD);
    asm volatile("s_waitcnt vmcnt(26)" ::: "memory");
    dsread(t + 1, A0, B0);
    step(A1, B1);
    if ((t & 31) == 0) renorm();
    ++t;
  }
  if (t <= nsteps) {   // odd leftover: (A0,B0) holds row t
    step(A0, B0);
  }

  sa[lane * 8 + 0] = a0; sa[lane * 8 + 1] = a1;
  sa[lane * 8 + 2] = a2; sa[lane * 8 + 3] = a3;
  sa[lane * 8 + 4] = a4; sa[lane * 8 + 5] = a5;
  sa[lane * 8 + 6] = a6; sa[lane * 8 + 7] = a7;
  __syncthreads();
  if (lane == 0) {
    int tl = tgt_len[n];
    double v = sa[2 * tl - 1] + sa[2 * tl];
    int ee;
    double m = frexp(v, &ee);
    nll_out[n] = -LN2_ * ((float)(Etot + ee) + log2f((float)m));
  }
}

__global__ void k_final(const float* __restrict__ nll,
                        const int* __restrict__ tgt_len,
                        float* __restrict__ out) {
  int lane = threadIdx.x;
  float v = 0.0f;
  if (lane < N_) v = nll[lane] / (float)tgt_len[lane];
#pragma unroll
  for (int i = 1; i < 64; i <<= 1) v += __shfl_xor(v, i);
  if (lane == 0) out[0] = v * (1.0f / N_);
}

__global__ void k_sentinel(float* out) { out[0] = -12345.0f; }

extern "C" void kernel_launch(void* const* d_in, const int* in_sizes, int n_in,
                              void* d_out, int out_size, void* d_ws, size_t ws_size,
                              hipStream_t stream) {
  const float* logits = (const float*)d_in[0];
  const int* targets  = (const int*)d_in[1];
  const int* in_len   = (const int*)d_in[2];
  const int* tgt_len  = (const int*)d_in[3];
  float* out = (float*)d_out;

  size_t gbytes = (size_t)N_ * T_ * LP_ * sizeof(float);  // ~104.9 MB
  if (ws_size < gbytes + 256) {
    k_sentinel<<<1, 1, 0, stream>>>(out);
    return;
  }
  float* G = (float*)d_ws;
  float* nll = (float*)((char*)d_ws + gbytes);

  k_softmax_gather<<<(N_ * T_) / 4, 256, 0, stream>>>(logits, targets, tgt_len, G);
  k_ctc<<<N_, 64, 0, stream>>>(G, targets, in_len, tgt_len, nll);
  k_final<<<1, 64, 0, stream>>>(nll, tgt_len, out);
}

// Round 4
// 438.884 us; speedup vs baseline: 2.1628x; 2.1628x over previous
//
#include <hip/hip_runtime.h>
#include <hip/hip_bf16.h>

#define N_    32
#define T_    1600
#define C_    1024
#define S_    200
#define L_    401       // 2*S+1
#define LP_   512       // padded
#define BLANK_ 4
#define LN2_  0.69314718055994531f
#define L2E_  1.44269504088896341f
#define DPF   8         // pipeline depth in rows (2 loads/row -> 16 in flight)

#if __has_builtin(__builtin_amdgcn_exp2f)
#define EXP2(x) __builtin_amdgcn_exp2f(x)
#else
#define EXP2(x) exp2f(x)
#endif
#if __has_builtin(__builtin_amdgcn_rcpf)
#define RCP(x) __builtin_amdgcn_rcpf(x)
#else
#define RCP(x) (1.0f / (x))
#endif

// Kernel 1: one wave per (n,t) row. Wave-shuffle softmax, row staged in LDS,
// gather ext-label classes, write LINEAR probabilities P[n][t][l].
// Junk positions (l > 2*tgt_len[n], never read) are zeroed so their alphas
// stay exactly 0 and never pollute the renorm max in k_ctc.
__global__ __launch_bounds__(256)
void k_softmax_gather(const float* __restrict__ logits,
                      const int* __restrict__ targets,
                      const int* __restrict__ tgt_len,
                      float* __restrict__ P) {
  const int row  = blockIdx.x * 4 + (threadIdx.x >> 6);  // n*T_ + t
  const int lane = threadIdx.x & 63;
  const int wv   = threadIdx.x >> 6;
  const int n    = row / T_;
  const float* x = logits + (size_t)row * C_;
  __shared__ float sh[4][C_];

  float4 v[4];
#pragma unroll
  for (int i = 0; i < 4; ++i)
    v[i] = reinterpret_cast<const float4*>(x)[i * 64 + lane];

  float mx = v[0].x;
#pragma unroll
  for (int i = 0; i < 4; ++i)
    mx = fmaxf(mx, fmaxf(fmaxf(v[i].x, v[i].y), fmaxf(v[i].z, v[i].w)));
#pragma unroll
  for (int i = 1; i < 64; i <<= 1) mx = fmaxf(mx, __shfl_xor(mx, i));

  float s = 0.0f;
#pragma unroll
  for (int i = 0; i < 4; ++i) {
    s += EXP2((v[i].x - mx) * L2E_) + EXP2((v[i].y - mx) * L2E_)
       + EXP2((v[i].z - mx) * L2E_) + EXP2((v[i].w - mx) * L2E_);
  }
#pragma unroll
  for (int i = 1; i < 64; i <<= 1) s += __shfl_xor(s, i);
  float rz = RCP(s);

#pragma unroll
  for (int i = 0; i < 4; ++i)
    reinterpret_cast<float4*>(sh[wv])[i * 64 + lane] = v[i];
  __syncthreads();

  const int* tg = targets + n * S_;
  const int lmax = 2 * tgt_len[n];   // live region: l in [0, 2*tl]
  float* out = P + (size_t)row * LP_;
#pragma unroll
  for (int i = 0; i < 8; ++i) {
    int l = lane + i * 64;
    float p = 0.0f;
    if (l <= lmax) {
      int c = (l & 1) ? tg[(l - 1) >> 1] : BLANK_;
      p = EXP2((sh[wv][c] - mx) * L2E_) * rz;
    }
    out[l] = p;
  }
}

// issue both 16B loads of one row via volatile asm: cannot be sunk, duplicated
// or rematerialized -> the software pipeline becomes a program property.
__device__ __forceinline__ void gload2(const float* p, float4& A, float4& B) {
  asm volatile("global_load_dwordx4 %0, %2, off\n\t"
               "global_load_dwordx4 %1, %2, off offset:16"
               : "=&v"(A), "=&v"(B)
               : "v"(p));
}

// counted wait + full scheduling fence (rule #18: the "memory" clobber alone
// does not order register-only f64 math past an asm waitcnt; sched_barrier(0)
// does). asm-volatile program order keeps loads/waits mutually ordered.
__device__ __forceinline__ void wait_vm14() {
  asm volatile("s_waitcnt vmcnt(14)" ::: "memory");
  __builtin_amdgcn_sched_barrier(0);
}

// Kernel 2: f64 linear-space CTC forward, ONE wave per sequence. Lane owns 8
// contiguous positions. Only ONE cross-lane value per step (alpha[l-1] for
// j=0), shuffled one step AHEAD so bpermute latency hides under the f64 issue
// stream.
//
// R1: compiler-generated prefetch sunk by reg-pressure heuristic (VGPR=84).
// R2: LDS-DMA ring -> compiler vmcnt(0) per ds_read, 930 cyc/step. R3: tied
// "+v" float4 asm operands don't compile on gfx950. THIS ROUND: volatile-asm
// global_load_dwordx4 pipeline (depth 8 rows / 16 loads in flight), each
// consumption gated by s_waitcnt vmcnt(14) + sched_barrier(0). Never vmcnt(0)
// in the main loop. Math / renorm cadence / epilogue counts identical to the
// verified R0/R1 kernels.
__global__ __launch_bounds__(64, 1)
void k_ctc(const float* __restrict__ P,
           const int* __restrict__ targets,
           const int* __restrict__ in_len,
           const int* __restrict__ tgt_len,
           float* __restrict__ nll_out) {
  const int n = blockIdx.x;
  const int lane = threadIdx.x;
  const int Tn = in_len[n];
  const float* g = P + (size_t)n * T_ * LP_;
  const int* tg = targets + n * S_;

  // skip multipliers for odd positions j=1,3,5,7 -> label index m0+0..3
  const int m0 = lane * 4;
  auto skv = [&](int m) -> double {
    int mi = (m >= 1 && m < S_) ? m : 1;     // clamp: no OOB read
    return (m >= 1 && m < S_ && tg[mi] != tg[mi - 1]) ? 1.0 : 0.0;
  };
  const double sk1 = skv(m0), sk3 = skv(m0 + 1);
  const double sk5 = skv(m0 + 2), sk7 = skv(m0 + 3);

  double a0 = 0.0, a1 = 0.0, a2 = 0.0, a3 = 0.0;
  double a4 = 0.0, a5 = 0.0, a6 = 0.0, a7 = 0.0;
  double up = 0.0;   // alpha(t-1, lane*8 - 1): shuffled during previous step
  if (lane == 0) { a0 = (double)g[0]; a1 = (double)g[1]; }
  int Etot = 0;      // true alpha = a * 2^Etot (wave-uniform)

  const float* gl = g + lane * 8;
  const int src = (lane + 63) & 63;

  auto step = [&](const float4& A, const float4& B) {
    // a7n/a6n first: lane-local only -> shuffle for NEXT step issues early
    double a7n = (a7 + a6 + sk7 * a5) * (double)B.w;
    double a6n = (a6 + a5) * (double)B.z;
    double upn = __shfl(a7n, src);           // consumed next step
    double a5n = (a5 + a4 + sk5 * a3) * (double)B.y;
    double a4n = (a4 + a3) * (double)B.x;
    double a3n = (a3 + a2 + sk3 * a1) * (double)A.w;
    double a2n = (a2 + a1) * (double)A.z;
    double a1n = (a1 + a0 + sk1 * up) * (double)A.y;  // up: already in regs
    double a0n = (a0 + up) * (double)A.x;             // even: no skip ever
    if (lane == 0) upn = 0.0;                // no predecessor
    a0 = a0n; a1 = a1n; a2 = a2n; a3 = a3n;
    a4 = a4n; a5 = a5n; a6 = a6n; a7 = a7n;
    up = upn;
  };

  auto renorm = [&]() {
    int h = max(max(max(__double2hiint(a0), __double2hiint(a1)),
                    max(__double2hiint(a2), __double2hiint(a3))),
                max(max(__double2hiint(a4), __double2hiint(a5)),
                    max(__double2hiint(a6), __double2hiint(a7))));
#pragma unroll
    for (int i = 1; i < 64; i <<= 1) h = max(h, __shfl_xor(h, i));
    int R = 1021 - (h >> 20);   // scale wave max into [2^-2, 2^-1)
    a0 = ldexp(a0, R); a1 = ldexp(a1, R); a2 = ldexp(a2, R); a3 = ldexp(a3, R);
    a4 = ldexp(a4, R); a5 = ldexp(a5, R); a6 = ldexp(a6, R); a7 = ldexp(a7, R);
    up = ldexp(up, R);          // pipelined boundary value rides along
    Etot -= R;
  };

  float4 A[DPF], B[DPF];
  // prologue: issue rows 1..8 (16 loads in flight; Tn >= 800 so all real)
#pragma unroll
  for (int d = 0; d < DPF; ++d)
    gload2(gl + (size_t)(1 + d) * LP_, A[d], B[d]);

  const int nsteps = Tn - 1;   // steps t = 1 .. Tn-1
  int t = 1;
  int blk = 0;
  while (t + (DPF - 1) <= nsteps) {
#pragma unroll
    for (int d = 0; d < DPF; ++d) {
      // oldest row (t+d) landed; 14 = 16 outstanding - 2 for this row.
      wait_vm14();
      step(A[d], B[d]);
      int tt = t + d + DPF;
      if (tt > T_ - 1) tt = T_ - 1;   // clamped rows: prefetch garbage, unused
      gload2(gl + (size_t)tt * LP_, A[d], B[d]);
    }
    t += DPF;
    if ((++blk & 3) == 0) renorm();   // every 32 steps; max gap 39 < f64 range
  }
  // epilogue: rem in [0, DPF-1] steps, rows t.. in slots 0..; drain all loads
  asm volatile("s_waitcnt vmcnt(0)" ::: "memory");
  __builtin_amdgcn_sched_barrier(0);
  {
    const int rem = nsteps - t + 1;
#pragma unroll
    for (int d = 0; d < DPF - 1; ++d) {
      if (d < rem) step(A[d], B[d]);
    }
  }

  __shared__ double sa[LP_];
  sa[lane * 8 + 0] = a0; sa[lane * 8 + 1] = a1;
  sa[lane * 8 + 2] = a2; sa[lane * 8 + 3] = a3;
  sa[lane * 8 + 4] = a4; sa[lane * 8 + 5] = a5;
  sa[lane * 8 + 6] = a6; sa[lane * 8 + 7] = a7;
  __syncthreads();
  if (lane == 0) {
    int tl = tgt_len[n];
    double v = sa[2 * tl - 1] + sa[2 * tl];
    int ee;
    double m = frexp(v, &ee);
    nll_out[n] = -LN2_ * ((float)(Etot + ee) + log2f((float)m));
  }
}

__global__ void k_final(const float* __restrict__ nll,
                        const int* __restrict__ tgt_len,
                        float* __restrict__ out) {
  int lane = threadIdx.x;
  float v = 0.0f;
  if (lane < N_) v = nll[lane] / (float)tgt_len[lane];
#pragma unroll
  for (int i = 1; i < 64; i <<= 1) v += __shfl_xor(v, i);
  if (lane == 0) out[0] = v * (1.0f / N_);
}

__global__ void k_sentinel(float* out) { out[0] = -12345.0f; }

extern "C" void kernel_launch(void* const* d_in, const int* in_sizes, int n_in,
                              void* d_out, int out_size, void* d_ws, size_t ws_size,
                              hipStream_t stream) {
  const float* logits = (const float*)d_in[0];
  const int* targets  = (const int*)d_in[1];
  const int* in_len   = (const int*)d_in[2];
  const int* tgt_len  = (const int*)d_in[3];
  float* out = (float*)d_out;

  size_t gbytes = (size_t)N_ * T_ * LP_ * sizeof(float);  // ~104.9 MB
  if (ws_size < gbytes + 256) {
    k_sentinel<<<1, 1, 0, stream>>>(out);
    return;
  }
  float* G = (float*)d_ws;
  float* nll = (float*)((char*)d_ws + gbytes);

  k_softmax_gather<<<(N_ * T_) / 4, 256, 0, stream>>>(logits, targets, tgt_len, G);
  k_ctc<<<N_, 64, 0, stream>>>(G, targets, in_len, tgt_len, nll);
  k_final<<<1, 64, 0, stream>>>(nll, tgt_len, out);
}